// Round 13
// baseline (600.070 us; speedup 1.0000x reference)
//
#include <hip/hip_runtime.h>
#include <hip/hip_fp16.h>

// ---------------------------------------------------------------------------
// Heads: per-head QKV projections + causal attention, B=4 T=1024 C=1024 H=8.
// Round 13: single persistent kernel (256 blocks = 1/CU, co-resident by LDS
// constraint) with hand-rolled device-scope grid barriers between stages:
//   SA: MT(128)+VT(0..127) = 256 units   -> bar
//   SB: Q'(512) = 2 units/block          -> bar
//   SC: QK(320)+VT(128..511) = 704 units -> bar
//   SM: distributed causal softmax (write-once; r12's 4x-dup writes were the
//       regression: cross-XCD same-address store storms)            -> bar
//   PV: r10 uniform pairing (20 K-units/block)
// GEMM tile core = round-10 verbatim (16x16x32, 8-phase counted vmcnt).
// Kills 5 dispatch boundaries + the standalone SM round-trip.
// ---------------------------------------------------------------------------

typedef unsigned short u16;
typedef _Float16 f16x8 __attribute__((ext_vector_type(8)));
typedef float f32x4 __attribute__((ext_vector_type(4)));

__device__ __forceinline__ u16 f2h(float f) {
    union { __half h; u16 u; } cv;
    cv.h = __float2half(f);
    return cv.u;
}
__device__ __forceinline__ float h2f(u16 u) {
    union { __half h; u16 u; } cv;
    cv.u = u;
    return __half2float(cv.h);
}

__device__ __forceinline__ void gload_lds16(const u16* g, const u16* lds_base, unsigned off_bytes) {
    unsigned a32 = (unsigned)(uintptr_t)((const char*)lds_base + off_bytes);
    a32 = __builtin_amdgcn_readfirstlane(a32);
    __builtin_amdgcn_global_load_lds(
        (const __attribute__((address_space(1))) void*)(uintptr_t)g,
        (__attribute__((address_space(3))) void*)a32,
        16, 0, 0);
}

// device-scope grid barrier: fresh counter per use (zeroed by cast_setup).
// All 256 blocks are co-resident (128 KB LDS -> 1 block/CU, grid == #CUs).
__device__ __forceinline__ void gridbar(unsigned* bar, int idx) {
    __syncthreads();
    if (threadIdx.x == 0) {
        __threadfence();   // release: L2 writeback to coherence point
        unsigned* c = bar + idx * 32;
        __hip_atomic_fetch_add(c, 1u, __ATOMIC_ACQ_REL, __HIP_MEMORY_SCOPE_AGENT);
        while (__hip_atomic_load(c, __ATOMIC_ACQUIRE, __HIP_MEMORY_SCOPE_AGENT) < 256u) {
            __builtin_amdgcn_s_sleep(2);
        }
        __threadfence();   // acquire: invalidate stale L2 lines
    }
    __syncthreads();
}

// ---------------------------------------------------------------------------
// gemm_tile: one 256x256xK tile, round-10 core verbatim. Operands [rows][K]
// fp16; Ab/Bb pre-offset to tile origin; outp pre-offset to output tile origin.
// ---------------------------------------------------------------------------
template <int F32OUT>
__device__ __forceinline__ void gemm_tile(
    const u16* __restrict__ Ab, const u16* __restrict__ Bb,
    int lda, int ldb, int NT, float scale, void* outp, int ldc, u16* lds)
{
    const int t = threadIdx.x, w = t >> 6, l = t & 63;
    const int wm = w >> 2, wn = w & 3;
    const int frow = l & 15, fch = l >> 4;
    const int clin = w * 64 + l;
    const int srow = clin >> 2;
    const int sch = (clin & 3) ^ ((clin >> 3) & 3);
    const long eA = (long)srow * lda + sch * 8;
    const long eB = (long)srow * ldb + sch * 8;

    f32x4 acc[8][4] = {};
    f16x8 af[4], bf[4];

#define STAGE(DB, MAT, KS, TT) do {                                            \
        const u16* g_ = (MAT == 0 ? Ab + (size_t)(TT) * 64 + (KS) * 32 + eA    \
                                  : Bb + (size_t)(TT) * 64 + (KS) * 32 + eB);  \
        const u16* hb_ = lds + ((((DB) << 2) | ((MAT) << 1) | (KS)) << 13);    \
        gload_lds16(g_, hb_, (unsigned)(w * 64 * 16));                         \
        gload_lds16(g_ + (size_t)128 * (MAT == 0 ? lda : ldb), hb_,            \
                    (unsigned)((512 + w * 64) * 16));                          \
    } while (0)

#define RD(DB, MAT, KS, ROW)                                                   \
    (*(const f16x8*)((const char*)(lds + ((((DB) << 2) | ((MAT) << 1) | (KS)) << 13)) + \
                     ((unsigned)((ROW) * 64 + fch * 16) ^ ((((ROW) >> 1) & 3) << 4))))

#define VM6 do { asm volatile("s_waitcnt vmcnt(6)"); \
                 __builtin_amdgcn_sched_barrier(0); } while (0)
#define VM0 do { asm volatile("s_waitcnt vmcnt(0)"); \
                 __builtin_amdgcn_sched_barrier(0); } while (0)
#define NOPW ((void)0)

#define PH(DB, KS, MH, WAITC, ...) do {                                        \
        if ((MH) == 0) {                                                       \
            _Pragma("unroll") for (int ni = 0; ni < 4; ++ni)                   \
                bf[ni] = RD(DB, 1, KS, wn * 64 + ni * 16 + frow);              \
        }                                                                      \
        _Pragma("unroll") for (int m4 = 0; m4 < 4; ++m4)                       \
            af[m4] = RD(DB, 0, KS, wm * 128 + ((MH) * 4 + m4) * 16 + frow);    \
        __VA_ARGS__;                                                           \
        __builtin_amdgcn_sched_barrier(0);                                     \
        __builtin_amdgcn_s_barrier();                                          \
        asm volatile("s_waitcnt lgkmcnt(0)");                                  \
        __builtin_amdgcn_sched_barrier(0);                                     \
        __builtin_amdgcn_s_setprio(1);                                         \
        _Pragma("unroll") for (int m4 = 0; m4 < 4; ++m4)                       \
            _Pragma("unroll") for (int ni = 0; ni < 4; ++ni)                   \
                acc[(MH) * 4 + m4][ni] = __builtin_amdgcn_mfma_f32_16x16x32_f16( \
                    af[m4], bf[ni], acc[(MH) * 4 + m4][ni], 0, 0, 0);          \
        __builtin_amdgcn_s_setprio(0);                                         \
        __builtin_amdgcn_sched_barrier(0);                                     \
        WAITC;                                                                 \
        __builtin_amdgcn_s_barrier();                                          \
    } while (0)

    // prologue: tile0 (4 halves) + tile1 (3 halves; A-ks1 issued at p0)
    STAGE(0, 1, 0, 0); STAGE(0, 0, 0, 0); STAGE(0, 1, 1, 0); STAGE(0, 0, 1, 0);
    STAGE(1, 1, 0, 1); STAGE(1, 0, 0, 1); STAGE(1, 1, 1, 1);
    VM6;
    __builtin_amdgcn_s_barrier();

    for (int tt = 0; tt < NT; tt += 2) {
        const bool more = (tt + 2) < NT;
        PH(0, 0, 0, NOPW, STAGE(1, 0, 1, tt + 1));              // p0
        PH(0, 0, 1, NOPW, if (more) STAGE(0, 1, 0, tt + 2));    // p1
        PH(0, 1, 0, NOPW, if (more) STAGE(0, 0, 0, tt + 2));    // p2
        PH(0, 1, 1, if (more) VM6; else VM0,
                    if (more) STAGE(0, 1, 1, tt + 2));          // p3
        PH(1, 0, 0, NOPW, if (more) STAGE(0, 0, 1, tt + 2));    // p4
        PH(1, 0, 1, NOPW, if (more) STAGE(1, 1, 0, tt + 3));    // p5
        PH(1, 1, 0, NOPW, if (more) STAGE(1, 0, 0, tt + 3));    // p6
        PH(1, 1, 1, if (more) VM6; else VM0,
                    if (more) STAGE(1, 1, 1, tt + 3));          // p7
    }
#undef PH
#undef RD
#undef STAGE
#undef VM6
#undef VM0
#undef NOPW

    // epilogue: C/D layout col = l&15, row = (l>>4)*4 + r
    const int r0 = (l >> 4) * 4, cc = l & 15;
#pragma unroll
    for (int mi = 0; mi < 8; ++mi) {
#pragma unroll
        for (int r = 0; r < 4; ++r) {
            size_t roff = (size_t)(wm * 128 + mi * 16 + r0 + r) * ldc;
#pragma unroll
            for (int ni = 0; ni < 4; ++ni) {
                int gcol = wn * 64 + ni * 16 + cc;
                float v = acc[mi][ni][r] * scale;
                if (F32OUT)
                    ((float*)outp)[roff + gcol] = v;
                else
                    ((u16*)outp)[roff + gcol] = f2h(v);
            }
        }
    }
}

// ---------------------------------------------------------------------------
// the persistent fused kernel
// ---------------------------------------------------------------------------
__global__ __launch_bounds__(512, 2) void fused(
    const u16* __restrict__ dataH, const u16* __restrict__ WvH,
    const u16* __restrict__ WqT, const u16* __restrict__ WkT,
    u16* __restrict__ MTp, u16* __restrict__ Qp, u16* __restrict__ VTa,
    u16* __restrict__ S16, u16* __restrict__ P16,
    float* __restrict__ outF, unsigned* __restrict__ bar)
{
    const int C = 1024, T = 1024, HC = 8192;
    __shared__ u16 lds[8 * 8192];
    const int phys = blockIdx.x;
    const int o = (phys & 7) * 32 + (phys >> 3);   // XCD-chunked remap

    // ---- SA: 256 units = MT(128) | VT tiles 0..127 ----
    {
        const u16 *Ab, *Bb; u16* op; int ldc2;
        if (o < 128) {
            const int h = o >> 4, r2 = o & 15, tm = r2 >> 2, tn = r2 & 3;
            Ab = WkT + (size_t)h * C * C + (size_t)tm * 256 * C;
            Bb = WqT + (size_t)h * C * C + (size_t)tn * 256 * C;
            op = MTp + (size_t)h * C * C + (size_t)tm * 256 * C + tn * 256;
            ldc2 = C;
        } else {
            const int v = o - 128, vz = v >> 4, rem = v & 15;
            const int tn = rem & 3, tm = rem >> 2;
            Ab = WvH + (size_t)(vz & 7) * C * C + (size_t)tm * 256 * C;
            Bb = dataH + (size_t)(vz >> 3) * T * C + (size_t)tn * 256 * C;
            op = VTa + (size_t)vz * C * T + (size_t)tm * 256 * T + tn * 256;
            ldc2 = T;
        }
        gemm_tile<0>(Ab, Bb, C, C, 16, 1.0f, op, ldc2, lds);
    }
    gridbar(bar, 0);

    // ---- SB: Q' 512 units, 2 per block ----
    for (int i = 0; i < 2; ++i) {
        const int u = o + (i << 8);
        const int s = u >> 6, ww = u & 63;
        const int tn = (s & 3) * 8 + (ww & 7);     // 0..31 (h = tn>>2)
        const int tm = (s >> 2) * 8 + (ww >> 3);   // 0..15
        const u16* Ab = dataH + (size_t)tm * 256 * C;
        const u16* Bb = MTp + (size_t)(tn >> 2) * C * C + (size_t)(tn & 3) * 256 * C;
        u16* op = Qp + (size_t)tm * 256 * HC + tn * 256;
        gemm_tile<0>(Ab, Bb, C, C, 16, 1.0f, op, HC, lds);
    }
    gridbar(bar, 1);

    // ---- SC: 704 units = QK(320) | VT tiles 128..511 ----
    for (int i = 0; i < 3; ++i) {
        const int u = o + (i << 8);
        if (u >= 704) break;
        const u16 *Ab, *Bb; u16* op; int lda2, ldc2; float sc;
        if (u < 320) {   // QK: S = Q' x X^T / 32, causal tiles
            const int qz = u / 10, j = u - qz * 10;
            const int tm = (j >= 1) + (j >= 3) + (j >= 6);
            const int tn = j - (tm == 0 ? 0 : tm == 1 ? 1 : tm == 2 ? 3 : 6);
            Ab = Qp + (size_t)(qz >> 3) * T * HC + (size_t)(qz & 7) * C
                    + (size_t)tm * 256 * HC;
            Bb = dataH + (size_t)(qz >> 3) * T * C + (size_t)tn * 256 * C;
            op = S16 + (size_t)qz * T * T + (size_t)tm * 256 * T + tn * 256;
            lda2 = HC; ldc2 = T; sc = 1.0f / 32.0f;
        } else {         // VT filler
            const int v = u - 320 + 128, vz = v >> 4, rem = v & 15;
            const int tn = rem & 3, tm = rem >> 2;
            Ab = WvH + (size_t)(vz & 7) * C * C + (size_t)tm * 256 * C;
            Bb = dataH + (size_t)(vz >> 3) * T * C + (size_t)tn * 256 * C;
            op = VTa + (size_t)vz * C * T + (size_t)tm * 256 * T + tn * 256;
            lda2 = C; ldc2 = T; sc = 1.0f;
        }
        gemm_tile<0>(Ab, Bb, lda2, C, 16, sc, op, ldc2, lds);
    }
    gridbar(bar, 2);

    // ---- SM: distributed causal softmax, write-once. rows rid = o + 256*i ----
    {
        const int w = threadIdx.x >> 6, l = threadIdx.x & 63;
        for (int i = w; i < 128; i += 8) {
            const int rid = o + (i << 8);
            const int z = rid >> 10, tq = rid & 1023;
            const u16* rp = S16 + ((size_t)z * T + tq) * T;
            u16* pp = P16 + ((size_t)z * T + tq) * T;
            const int nvalid = tq + 1;
            const int nseg = (tq >> 8) + 1;   // 256-col segments live
            float ev[16];
#pragma unroll
            for (int j = 0; j < 4; ++j) {
                const int col = j * 256 + l * 4;
                if (j < nseg) {
                    ushort4 v4 = *(const ushort4*)(rp + col);
                    ev[j * 4 + 0] = (col + 0 < nvalid) ? h2f(v4.x) : -3.0e38f;
                    ev[j * 4 + 1] = (col + 1 < nvalid) ? h2f(v4.y) : -3.0e38f;
                    ev[j * 4 + 2] = (col + 2 < nvalid) ? h2f(v4.z) : -3.0e38f;
                    ev[j * 4 + 3] = (col + 3 < nvalid) ? h2f(v4.w) : -3.0e38f;
                } else {
                    ev[j * 4 + 0] = -3.0e38f; ev[j * 4 + 1] = -3.0e38f;
                    ev[j * 4 + 2] = -3.0e38f; ev[j * 4 + 3] = -3.0e38f;
                }
            }
            float mx = -3.0e38f;
#pragma unroll
            for (int e = 0; e < 16; ++e) mx = fmaxf(mx, ev[e]);
#pragma unroll
            for (int od = 1; od < 64; od <<= 1) mx = fmaxf(mx, __shfl_xor(mx, od));
            float sum = 0.f;
#pragma unroll
            for (int e = 0; e < 16; ++e) { ev[e] = __expf(ev[e] - mx); sum += ev[e]; }
#pragma unroll
            for (int od = 1; od < 64; od <<= 1) sum += __shfl_xor(sum, od);
            const float inv = 1.0f / sum;
#pragma unroll
            for (int j = 0; j < 4; ++j) {
                const int col = j * 256 + l * 4;
                if (j < nseg) {
                    ushort4 o4;
                    o4.x = f2h(ev[j * 4 + 0] * inv);
                    o4.y = f2h(ev[j * 4 + 1] * inv);
                    o4.z = f2h(ev[j * 4 + 2] * inv);
                    o4.w = f2h(ev[j * 4 + 3] * inv);
                    *(ushort4*)(pp + col) = o4;
                }
            }
        }
    }
    gridbar(bar, 3);

    // ---- PV: 2 passes, uniform 20 K-units/block (pairs (3,hi?2) / (0,hi?1)) ----
    for (int pass = 0; pass < 2; ++pass) {
        const int pz = o >> 3, j = o & 7, x = j & 3, hi = j >> 2;
        const int tm = (pass == 0) ? (hi ? 2 : 3) : (hi ? 1 : 0);
        const u16* Ab = P16 + (size_t)pz * T * T + (size_t)tm * 256 * T;
        const u16* Bb = VTa + (size_t)pz * C * T + (size_t)x * 256 * T;
        float* op = outF + (size_t)(pz >> 3) * T * HC + (size_t)(pz & 7) * C
                         + (size_t)tm * 256 * HC + x * 256;
        gemm_tile<1>(Ab, Bb, T, T, (tm + 1) * 4, 1.0f, op, HC, lds);
    }
}

// ---------------------------------------------------------------------------
// setup: z<16 -> per-head transpose-cast of Wq/Wk; z==16 -> data cast;
// z==17 -> Wv cast (+ zero the grid-barrier counters).
// ---------------------------------------------------------------------------
__global__ __launch_bounds__(256) void cast_setup(
    const float* __restrict__ data, const float* __restrict__ Wq,
    const float* __restrict__ Wk, const float* __restrict__ Wv,
    u16* __restrict__ dataH, u16* __restrict__ WqT,
    u16* __restrict__ WkT, u16* __restrict__ WvH, unsigned* __restrict__ bar)
{
    const int z = blockIdx.z, tx = threadIdx.x, ty = threadIdx.y;
    if (z == 17 && blockIdx.x == 0 && blockIdx.y == 0 && tx == 0 && ty == 0) {
        bar[0] = 0; bar[32] = 0; bar[64] = 0; bar[96] = 0;
    }
    if (z < 16) {
        const int h = z & 7;
        const float* src = ((z >> 3) ? Wk : Wq) + (size_t)h * 1048576;
        u16* dst = ((z >> 3) ? WkT : WqT) + (size_t)h * 1048576;
        const int r0 = blockIdx.y * 32, c0 = blockIdx.x * 32;
        __shared__ float tile[32][33];
        for (int i = ty; i < 32; i += 8)
            tile[i][tx] = src[(size_t)(r0 + i) * 1024 + c0 + tx];
        __syncthreads();
        for (int i = ty; i < 32; i += 8)
            dst[(size_t)(c0 + i) * 1024 + r0 + tx] = f2h(tile[tx][i]);
    } else {
        const int tid = ty * 32 + tx;
        const int bid = blockIdx.y * 32 + blockIdx.x;   // 0..1023
        const int reps = (z == 16) ? 4 : 8;             // 1M / 2M float4
        const float* src = (z == 16) ? data : Wv;
        u16* dst = (z == 16) ? dataH : WvH;
        for (int k2 = 0; k2 < reps; ++k2) {
            int i = (k2 * 1024 + bid) * 256 + tid;
            float4 v = ((const float4*)src)[i];
            ushort4 o4;
            o4.x = f2h(v.x); o4.y = f2h(v.y); o4.z = f2h(v.z); o4.w = f2h(v.w);
            ((ushort4*)dst)[i] = o4;
        }
    }
}

extern "C" void kernel_launch(void* const* d_in, const int* in_sizes, int n_in,
                              void* d_out, int out_size, void* d_ws, size_t ws_size,
                              hipStream_t stream)
{
    (void)in_sizes; (void)n_in; (void)out_size; (void)ws_size;
    const int B = 4, T = 1024, C = 1024, H = 8;
    const int BT = B * T, HC = H * C;

    const float* data = (const float*)d_in[0];
    const float* Wq = (const float*)d_in[1];
    const float* Wk = (const float*)d_in[2];
    const float* Wv = (const float*)d_in[3];
    float* out = (float*)d_out;

    // workspace (328 MiB + barrier page of 512 MiB)
    char* p = (char*)d_ws;
    const size_t nData = (size_t)BT * C;      // 4M
    const size_t nW = (size_t)H * C * C;      // 8M
    const size_t nAll = (size_t)BT * HC;      // 32M
    const size_t nS = (size_t)B * H * T * T;  // 32M
    u16* dataH = (u16*)p; p += nData * 2;     //   8 MiB
    u16* WvH = (u16*)p; p += nW * 2;          //  16 MiB
    u16* WqT = (u16*)p; p += nW * 2;          //  16 MiB
    u16* WkT = (u16*)p; p += nW * 2;          //  16 MiB
    u16* MTp = (u16*)p; p += nW * 2;          //  16 MiB
    u16* Qp = (u16*)p; p += nAll * 2;         //  64 MiB
    u16* VTa = (u16*)p; p += nAll * 2;        //  64 MiB
    u16* S16 = (u16*)p; p += nS * 2;          //  64 MiB
    u16* P16 = (u16*)p; p += nS * 2;          //  64 MiB
    unsigned* bar = (unsigned*)(((uintptr_t)p + 255) & ~(uintptr_t)255);

    cast_setup<<<dim3(32, 32, 18), dim3(32, 8), 0, stream>>>(
        data, Wq, Wk, Wv, dataH, WqT, WkT, WvH, bar);

    fused<<<dim3(256), dim3(512), 0, stream>>>(
        dataH, WvH, WqT, WkT, MTp, Qp, VTa, S16, P16, out, bar);
}

// Round 14
// 585.207 us; speedup vs baseline: 1.0254x; 1.0254x over previous
//
#include <hip/hip_runtime.h>
#include <hip/hip_fp16.h>

// ---------------------------------------------------------------------------
// Heads: per-head QKV projections + causal attention, B=4 T=1024 C=1024 H=8.
// Round 13: single persistent kernel (256 blocks = 1/CU, co-resident by LDS
// constraint) with hand-rolled device-scope grid barriers between stages:
//   SA: MT(128)+VT(0..127) = 256 units   -> bar
//   SB: Q'(512) = 2 units/block          -> bar
//   SC: QK(320)+VT(128..511) = 704 units -> bar
//   SM: distributed causal softmax (write-once; r12's 4x-dup writes were the
//       regression: cross-XCD same-address store storms)            -> bar
//   PV: r10 uniform pairing (20 K-units/block)
// GEMM tile core = round-10 verbatim (16x16x32, 8-phase counted vmcnt).
// Kills 5 dispatch boundaries + the standalone SM round-trip.
// ---------------------------------------------------------------------------

typedef unsigned short u16;
typedef _Float16 f16x8 __attribute__((ext_vector_type(8)));
typedef float f32x4 __attribute__((ext_vector_type(4)));

__device__ __forceinline__ u16 f2h(float f) {
    union { __half h; u16 u; } cv;
    cv.h = __float2half(f);
    return cv.u;
}
__device__ __forceinline__ float h2f(u16 u) {
    union { __half h; u16 u; } cv;
    cv.u = u;
    return __half2float(cv.h);
}

__device__ __forceinline__ void gload_lds16(const u16* g, const u16* lds_base, unsigned off_bytes) {
    unsigned a32 = (unsigned)(uintptr_t)((const char*)lds_base + off_bytes);
    a32 = __builtin_amdgcn_readfirstlane(a32);
    __builtin_amdgcn_global_load_lds(
        (const __attribute__((address_space(1))) void*)(uintptr_t)g,
        (__attribute__((address_space(3))) void*)a32,
        16, 0, 0);
}

// device-scope grid barrier: fresh counter per use (zeroed by cast_setup).
// All 256 blocks are co-resident (128 KB LDS -> 1 block/CU, grid == #CUs).
__device__ __forceinline__ void gridbar(unsigned* bar, int idx) {
    __syncthreads();
    if (threadIdx.x == 0) {
        __threadfence();   // release: L2 writeback to coherence point
        unsigned* c = bar + idx * 32;
        __hip_atomic_fetch_add(c, 1u, __ATOMIC_ACQ_REL, __HIP_MEMORY_SCOPE_AGENT);
        while (__hip_atomic_load(c, __ATOMIC_ACQUIRE, __HIP_MEMORY_SCOPE_AGENT) < 256u) {
            __builtin_amdgcn_s_sleep(2);
        }
        __threadfence();   // acquire: invalidate stale L2 lines
    }
    __syncthreads();
}

// ---------------------------------------------------------------------------
// gemm_tile: one 256x256xK tile, round-10 core verbatim. Operands [rows][K]
// fp16; Ab/Bb pre-offset to tile origin; outp pre-offset to output tile origin.
// ---------------------------------------------------------------------------
template <int F32OUT>
__device__ __forceinline__ void gemm_tile(
    const u16* __restrict__ Ab, const u16* __restrict__ Bb,
    int lda, int ldb, int NT, float scale, void* outp, int ldc, u16* lds)
{
    const int t = threadIdx.x, w = t >> 6, l = t & 63;
    const int wm = w >> 2, wn = w & 3;
    const int frow = l & 15, fch = l >> 4;
    const int clin = w * 64 + l;
    const int srow = clin >> 2;
    const int sch = (clin & 3) ^ ((clin >> 3) & 3);
    const long eA = (long)srow * lda + sch * 8;
    const long eB = (long)srow * ldb + sch * 8;

    f32x4 acc[8][4] = {};
    f16x8 af[4], bf[4];

#define STAGE(DB, MAT, KS, TT) do {                                            \
        const u16* g_ = (MAT == 0 ? Ab + (size_t)(TT) * 64 + (KS) * 32 + eA    \
                                  : Bb + (size_t)(TT) * 64 + (KS) * 32 + eB);  \
        const u16* hb_ = lds + ((((DB) << 2) | ((MAT) << 1) | (KS)) << 13);    \
        gload_lds16(g_, hb_, (unsigned)(w * 64 * 16));                         \
        gload_lds16(g_ + (size_t)128 * (MAT == 0 ? lda : ldb), hb_,            \
                    (unsigned)((512 + w * 64) * 16));                          \
    } while (0)

#define RD(DB, MAT, KS, ROW)                                                   \
    (*(const f16x8*)((const char*)(lds + ((((DB) << 2) | ((MAT) << 1) | (KS)) << 13)) + \
                     ((unsigned)((ROW) * 64 + fch * 16) ^ ((((ROW) >> 1) & 3) << 4))))

#define VM6 do { asm volatile("s_waitcnt vmcnt(6)"); \
                 __builtin_amdgcn_sched_barrier(0); } while (0)
#define VM0 do { asm volatile("s_waitcnt vmcnt(0)"); \
                 __builtin_amdgcn_sched_barrier(0); } while (0)
#define NOPW ((void)0)

#define PH(DB, KS, MH, WAITC, ...) do {                                        \
        if ((MH) == 0) {                                                       \
            _Pragma("unroll") for (int ni = 0; ni < 4; ++ni)                   \
                bf[ni] = RD(DB, 1, KS, wn * 64 + ni * 16 + frow);              \
        }                                                                      \
        _Pragma("unroll") for (int m4 = 0; m4 < 4; ++m4)                       \
            af[m4] = RD(DB, 0, KS, wm * 128 + ((MH) * 4 + m4) * 16 + frow);    \
        __VA_ARGS__;                                                           \
        __builtin_amdgcn_sched_barrier(0);                                     \
        __builtin_amdgcn_s_barrier();                                          \
        asm volatile("s_waitcnt lgkmcnt(0)");                                  \
        __builtin_amdgcn_sched_barrier(0);                                     \
        __builtin_amdgcn_s_setprio(1);                                         \
        _Pragma("unroll") for (int m4 = 0; m4 < 4; ++m4)                       \
            _Pragma("unroll") for (int ni = 0; ni < 4; ++ni)                   \
                acc[(MH) * 4 + m4][ni] = __builtin_amdgcn_mfma_f32_16x16x32_f16( \
                    af[m4], bf[ni], acc[(MH) * 4 + m4][ni], 0, 0, 0);          \
        __builtin_amdgcn_s_setprio(0);                                         \
        __builtin_amdgcn_sched_barrier(0);                                     \
        WAITC;                                                                 \
        __builtin_amdgcn_s_barrier();                                          \
    } while (0)

    // prologue: tile0 (4 halves) + tile1 (3 halves; A-ks1 issued at p0)
    STAGE(0, 1, 0, 0); STAGE(0, 0, 0, 0); STAGE(0, 1, 1, 0); STAGE(0, 0, 1, 0);
    STAGE(1, 1, 0, 1); STAGE(1, 0, 0, 1); STAGE(1, 1, 1, 1);
    VM6;
    __builtin_amdgcn_s_barrier();

    for (int tt = 0; tt < NT; tt += 2) {
        const bool more = (tt + 2) < NT;
        PH(0, 0, 0, NOPW, STAGE(1, 0, 1, tt + 1));              // p0
        PH(0, 0, 1, NOPW, if (more) STAGE(0, 1, 0, tt + 2));    // p1
        PH(0, 1, 0, NOPW, if (more) STAGE(0, 0, 0, tt + 2));    // p2
        PH(0, 1, 1, if (more) VM6; else VM0,
                    if (more) STAGE(0, 1, 1, tt + 2));          // p3
        PH(1, 0, 0, NOPW, if (more) STAGE(0, 0, 1, tt + 2));    // p4
        PH(1, 0, 1, NOPW, if (more) STAGE(1, 1, 0, tt + 3));    // p5
        PH(1, 1, 0, NOPW, if (more) STAGE(1, 0, 0, tt + 3));    // p6
        PH(1, 1, 1, if (more) VM6; else VM0,
                    if (more) STAGE(1, 1, 1, tt + 3));          // p7
    }
#undef PH
#undef RD
#undef STAGE
#undef VM6
#undef VM0
#undef NOPW

    // epilogue: C/D layout col = l&15, row = (l>>4)*4 + r
    const int r0 = (l >> 4) * 4, cc = l & 15;
#pragma unroll
    for (int mi = 0; mi < 8; ++mi) {
#pragma unroll
        for (int r = 0; r < 4; ++r) {
            size_t roff = (size_t)(wm * 128 + mi * 16 + r0 + r) * ldc;
#pragma unroll
            for (int ni = 0; ni < 4; ++ni) {
                int gcol = wn * 64 + ni * 16 + cc;
                float v = acc[mi][ni][r] * scale;
                if (F32OUT)
                    ((float*)outp)[roff + gcol] = v;
                else
                    ((u16*)outp)[roff + gcol] = f2h(v);
            }
        }
    }
}

// ---------------------------------------------------------------------------
// the persistent fused kernel
// ---------------------------------------------------------------------------
__global__ __launch_bounds__(512, 2) void fused(
    const u16* __restrict__ dataH, const u16* __restrict__ WvH,
    const u16* __restrict__ WqT, const u16* __restrict__ WkT,
    u16* __restrict__ MTp, u16* __restrict__ Qp, u16* __restrict__ VTa,
    u16* __restrict__ S16, u16* __restrict__ P16,
    float* __restrict__ outF, unsigned* __restrict__ bar)
{
    const int C = 1024, T = 1024, HC = 8192;
    __shared__ u16 lds[8 * 8192];
    const int phys = blockIdx.x;
    const int o = (phys & 7) * 32 + (phys >> 3);   // XCD-chunked remap

    // ---- SA: 256 units = MT(128) | VT tiles 0..127 ----
    {
        const u16 *Ab, *Bb; u16* op; int ldc2;
        if (o < 128) {
            const int h = o >> 4, r2 = o & 15, tm = r2 >> 2, tn = r2 & 3;
            Ab = WkT + (size_t)h * C * C + (size_t)tm * 256 * C;
            Bb = WqT + (size_t)h * C * C + (size_t)tn * 256 * C;
            op = MTp + (size_t)h * C * C + (size_t)tm * 256 * C + tn * 256;
            ldc2 = C;
        } else {
            const int v = o - 128, vz = v >> 4, rem = v & 15;
            const int tn = rem & 3, tm = rem >> 2;
            Ab = WvH + (size_t)(vz & 7) * C * C + (size_t)tm * 256 * C;
            Bb = dataH + (size_t)(vz >> 3) * T * C + (size_t)tn * 256 * C;
            op = VTa + (size_t)vz * C * T + (size_t)tm * 256 * T + tn * 256;
            ldc2 = T;
        }
        gemm_tile<0>(Ab, Bb, C, C, 16, 1.0f, op, ldc2, lds);
    }
    gridbar(bar, 0);

    // ---- SB: Q' 512 units, 2 per block ----
    for (int i = 0; i < 2; ++i) {
        const int u = o + (i << 8);
        const int s = u >> 6, ww = u & 63;
        const int tn = (s & 3) * 8 + (ww & 7);     // 0..31 (h = tn>>2)
        const int tm = (s >> 2) * 8 + (ww >> 3);   // 0..15
        const u16* Ab = dataH + (size_t)tm * 256 * C;
        const u16* Bb = MTp + (size_t)(tn >> 2) * C * C + (size_t)(tn & 3) * 256 * C;
        u16* op = Qp + (size_t)tm * 256 * HC + tn * 256;
        gemm_tile<0>(Ab, Bb, C, C, 16, 1.0f, op, HC, lds);
    }
    gridbar(bar, 1);

    // ---- SC: 704 units = QK(320) | VT tiles 128..511 ----
    for (int i = 0; i < 3; ++i) {
        const int u = o + (i << 8);
        if (u >= 704) break;
        const u16 *Ab, *Bb; u16* op; int lda2, ldc2; float sc;
        if (u < 320) {   // QK: S = Q' x X^T / 32, causal tiles
            const int qz = u / 10, j = u - qz * 10;
            const int tm = (j >= 1) + (j >= 3) + (j >= 6);
            const int tn = j - (tm == 0 ? 0 : tm == 1 ? 1 : tm == 2 ? 3 : 6);
            Ab = Qp + (size_t)(qz >> 3) * T * HC + (size_t)(qz & 7) * C
                    + (size_t)tm * 256 * HC;
            Bb = dataH + (size_t)(qz >> 3) * T * C + (size_t)tn * 256 * C;
            op = S16 + (size_t)qz * T * T + (size_t)tm * 256 * T + tn * 256;
            lda2 = HC; ldc2 = T; sc = 1.0f / 32.0f;
        } else {         // VT filler
            const int v = u - 320 + 128, vz = v >> 4, rem = v & 15;
            const int tn = rem & 3, tm = rem >> 2;
            Ab = WvH + (size_t)(vz & 7) * C * C + (size_t)tm * 256 * C;
            Bb = dataH + (size_t)(vz >> 3) * T * C + (size_t)tn * 256 * C;
            op = VTa + (size_t)vz * C * T + (size_t)tm * 256 * T + tn * 256;
            lda2 = C; ldc2 = T; sc = 1.0f;
        }
        gemm_tile<0>(Ab, Bb, lda2, C, 16, sc, op, ldc2, lds);
    }
    gridbar(bar, 2);

    // ---- SM: distributed causal softmax, write-once. rows rid = o + 256*i ----
    {
        const int w = threadIdx.x >> 6, l = threadIdx.x & 63;
        for (int i = w; i < 128; i += 8) {
            const int rid = o + (i << 8);
            const int z = rid >> 10, tq = rid & 1023;
            const u16* rp = S16 + ((size_t)z * T + tq) * T;
            u16* pp = P16 + ((size_t)z * T + tq) * T;
            const int nvalid = tq + 1;
            const int nseg = (tq >> 8) + 1;   // 256-col segments live
            float ev[16];
#pragma unroll
            for (int j = 0; j < 4; ++j) {
                const int col = j * 256 + l * 4;
                if (j < nseg) {
                    ushort4 v4 = *(const ushort4*)(rp + col);
                    ev[j * 4 + 0] = (col + 0 < nvalid) ? h2f(v4.x) : -3.0e38f;
                    ev[j * 4 + 1] = (col + 1 < nvalid) ? h2f(v4.y) : -3.0e38f;
                    ev[j * 4 + 2] = (col + 2 < nvalid) ? h2f(v4.z) : -3.0e38f;
                    ev[j * 4 + 3] = (col + 3 < nvalid) ? h2f(v4.w) : -3.0e38f;
                } else {
                    ev[j * 4 + 0] = -3.0e38f; ev[j * 4 + 1] = -3.0e38f;
                    ev[j * 4 + 2] = -3.0e38f; ev[j * 4 + 3] = -3.0e38f;
                }
            }
            float mx = -3.0e38f;
#pragma unroll
            for (int e = 0; e < 16; ++e) mx = fmaxf(mx, ev[e]);
#pragma unroll
            for (int od = 1; od < 64; od <<= 1) mx = fmaxf(mx, __shfl_xor(mx, od));
            float sum = 0.f;
#pragma unroll
            for (int e = 0; e < 16; ++e) { ev[e] = __expf(ev[e] - mx); sum += ev[e]; }
#pragma unroll
            for (int od = 1; od < 64; od <<= 1) sum += __shfl_xor(sum, od);
            const float inv = 1.0f / sum;
#pragma unroll
            for (int j = 0; j < 4; ++j) {
                const int col = j * 256 + l * 4;
                if (j < nseg) {
                    ushort4 o4;
                    o4.x = f2h(ev[j * 4 + 0] * inv);
                    o4.y = f2h(ev[j * 4 + 1] * inv);
                    o4.z = f2h(ev[j * 4 + 2] * inv);
                    o4.w = f2h(ev[j * 4 + 3] * inv);
                    *(ushort4*)(pp + col) = o4;
                }
            }
        }
    }
    gridbar(bar, 3);

    // ---- PV: 2 passes, uniform 20 K-units/block (pairs (3,hi?2) / (0,hi?1)) ----
    for (int pass = 0; pass < 2; ++pass) {
        const int pz = o >> 3, j = o & 7, x = j & 3, hi = j >> 2;
        const int tm = (pass == 0) ? (hi ? 2 : 3) : (hi ? 1 : 0);
        const u16* Ab = P16 + (size_t)pz * T * T + (size_t)tm * 256 * T;
        const u16* Bb = VTa + (size_t)pz * C * T + (size_t)x * 256 * T;
        float* op = outF + (size_t)(pz >> 3) * T * HC + (size_t)(pz & 7) * C
                         + (size_t)tm * 256 * HC + x * 256;
        gemm_tile<1>(Ab, Bb, T, T, (tm + 1) * 4, 1.0f, op, HC, lds);
    }
}

// ---------------------------------------------------------------------------
// setup: z<16 -> per-head transpose-cast of Wq/Wk; z==16 -> data cast;
// z==17 -> Wv cast (+ zero the grid-barrier counters).
// ---------------------------------------------------------------------------
__global__ __launch_bounds__(256) void cast_setup(
    const float* __restrict__ data, const float* __restrict__ Wq,
    const float* __restrict__ Wk, const float* __restrict__ Wv,
    u16* __restrict__ dataH, u16* __restrict__ WqT,
    u16* __restrict__ WkT, u16* __restrict__ WvH, unsigned* __restrict__ bar)
{
    const int z = blockIdx.z, tx = threadIdx.x, ty = threadIdx.y;
    if (z == 17 && blockIdx.x == 0 && blockIdx.y == 0 && tx == 0 && ty == 0) {
        bar[0] = 0; bar[32] = 0; bar[64] = 0; bar[96] = 0;
    }
    if (z < 16) {
        const int h = z & 7;
        const float* src = ((z >> 3) ? Wk : Wq) + (size_t)h * 1048576;
        u16* dst = ((z >> 3) ? WkT : WqT) + (size_t)h * 1048576;
        const int r0 = blockIdx.y * 32, c0 = blockIdx.x * 32;
        __shared__ float tile[32][33];
        for (int i = ty; i < 32; i += 8)
            tile[i][tx] = src[(size_t)(r0 + i) * 1024 + c0 + tx];
        __syncthreads();
        for (int i = ty; i < 32; i += 8)
            dst[(size_t)(c0 + i) * 1024 + r0 + tx] = f2h(tile[tx][i]);
    } else {
        const int tid = ty * 32 + tx;
        const int bid = blockIdx.y * 32 + blockIdx.x;   // 0..1023
        const int reps = (z == 16) ? 4 : 8;             // 1M / 2M float4
        const float* src = (z == 16) ? data : Wv;
        u16* dst = (z == 16) ? dataH : WvH;
        for (int k2 = 0; k2 < reps; ++k2) {
            int i = (k2 * 1024 + bid) * 256 + tid;
            float4 v = ((const float4*)src)[i];
            ushort4 o4;
            o4.x = f2h(v.x); o4.y = f2h(v.y); o4.z = f2h(v.z); o4.w = f2h(v.w);
            ((ushort4*)dst)[i] = o4;
        }
    }
}

extern "C" void kernel_launch(void* const* d_in, const int* in_sizes, int n_in,
                              void* d_out, int out_size, void* d_ws, size_t ws_size,
                              hipStream_t stream)
{
    (void)in_sizes; (void)n_in; (void)out_size; (void)ws_size;
    const int B = 4, T = 1024, C = 1024, H = 8;
    const int BT = B * T, HC = H * C;

    const float* data = (const float*)d_in[0];
    const float* Wq = (const float*)d_in[1];
    const float* Wk = (const float*)d_in[2];
    const float* Wv = (const float*)d_in[3];
    float* out = (float*)d_out;

    // workspace (328 MiB + barrier page of 512 MiB)
    char* p = (char*)d_ws;
    const size_t nData = (size_t)BT * C;      // 4M
    const size_t nW = (size_t)H * C * C;      // 8M
    const size_t nAll = (size_t)BT * HC;      // 32M
    const size_t nS = (size_t)B * H * T * T;  // 32M
    u16* dataH = (u16*)p; p += nData * 2;     //   8 MiB
    u16* WvH = (u16*)p; p += nW * 2;          //  16 MiB
    u16* WqT = (u16*)p; p += nW * 2;          //  16 MiB
    u16* WkT = (u16*)p; p += nW * 2;          //  16 MiB
    u16* MTp = (u16*)p; p += nW * 2;          //  16 MiB
    u16* Qp = (u16*)p; p += nAll * 2;         //  64 MiB
    u16* VTa = (u16*)p; p += nAll * 2;        //  64 MiB
    u16* S16 = (u16*)p; p += nS * 2;          //  64 MiB
    u16* P16 = (u16*)p; p += nS * 2;          //  64 MiB
    unsigned* bar = (unsigned*)(((uintptr_t)p + 255) & ~(uintptr_t)255);

    cast_setup<<<dim3(32, 32, 18), dim3(32, 8), 0, stream>>>(
        data, Wq, Wk, Wv, dataH, WqT, WkT, WvH, bar);

    fused<<<dim3(256), dim3(512), 0, stream>>>(
        dataH, WvH, WqT, WkT, MTp, Qp, VTa, S16, P16, out, bar);
}